// Round 13
// baseline (130.188 us; speedup 1.0000x reference)
//
#include <hip/hip_runtime.h>
#include <math.h>

#define LOG2PI_F  0.9189385332046727f
#define INV_LN2_F 1.4426950408889634f
#define LN2_F     0.6931471805599453f
#define SROW      72          // slot row stride in shorts (144B, 16B-aligned rows)

typedef short bf16x8 __attribute__((ext_vector_type(8)));
typedef float f32x4  __attribute__((ext_vector_type(4)));

struct __align__(16) Op { int w; int c0; int c1; int pad; };

// ---- workspace byte offsets -------------------------------------------------
#define WS_WBJ   0u          // bf16[255][8 frag][64 lane][8] pre-swizzled weights
#define WS_A     2097152u    // float[256*64]  leaf coeff A (log2 domain)
#define WS_B     2162688u    // float[256*64]  leaf coeff B
#define WS_C     2228224u    // float[256*64]  leaf coeff C
#define WS_XT    2293760u    // float[256*2048] x gathered+transposed: xT[d][b]
#define WS_SCHED 4390912u    // Op[16*15 @0 .. K14 trees, 15 @240 .. tail L5-8]
#define WS_L4A   4395008u    // bf16[16*2048*64] level-4 acc values
#define WS_L4M   8589312u    // float[16*2048]   level-4 row scales (log2)

// All f32->bf16 conversions use the proven integer-RNE path (R2 lesson:
// v_cvt_pk_bf16_f32 inline asm produced NaN poison on this toolchain).
__device__ __forceinline__ short bfr(float f) {   // f32 -> bf16 RNE
    unsigned int u = __float_as_uint(f);
    u += 0x7fffu + ((u >> 16) & 1u);
    return (short)(u >> 16);
}

__device__ __forceinline__ unsigned pk2(float a, float b) {  // lo=bf16(a) hi=bf16(b)
    return (unsigned)(unsigned short)bfr(a) | ((unsigned)(unsigned short)bfr(b) << 16);
}

struct F8v { float v[8]; };
__device__ __forceinline__ F8v ld8(const float* p) {
    F8v r;
    float4 a = *(const float4*)p;
    float4 b = *(const float4*)(p + 4);
    r.v[0]=a.x; r.v[1]=a.y; r.v[2]=a.z; r.v[3]=a.w;
    r.v[4]=b.x; r.v[5]=b.y; r.v[6]=b.z; r.v[7]=b.w;
    return r;
}

__device__ __forceinline__ void up8(int4 v, float* o) {   // 8 bf16 -> f32
    o[0] = __uint_as_float(((unsigned)v.x) << 16);
    o[1] = __uint_as_float(((unsigned)v.x) & 0xffff0000u);
    o[2] = __uint_as_float(((unsigned)v.y) << 16);
    o[3] = __uint_as_float(((unsigned)v.y) & 0xffff0000u);
    o[4] = __uint_as_float(((unsigned)v.z) << 16);
    o[5] = __uint_as_float(((unsigned)v.z) & 0xffff0000u);
    o[6] = __uint_as_float(((unsigned)v.w) << 16);
    o[7] = __uint_as_float(((unsigned)v.w) & 0xffff0000u);
}

__device__ __forceinline__ float rmax16(const float hv[16]) {
    float m01 = fmaxf(hv[0], hv[1]),  m23 = fmaxf(hv[2], hv[3]);
    float m45 = fmaxf(hv[4], hv[5]),  m67 = fmaxf(hv[6], hv[7]);
    float m89 = fmaxf(hv[8], hv[9]),  mab = fmaxf(hv[10], hv[11]);
    float mcd = fmaxf(hv[12], hv[13]), mef = fmaxf(hv[14], hv[15]);
    float hm = fmaxf(fmaxf(fmaxf(m01, m23), fmaxf(m45, m67)),
                     fmaxf(fmaxf(m89, mab), fmaxf(mcd, mef)));
    hm = fmaxf(hm, __shfl_xor(hm, 16, 64));
    hm = fmaxf(hm, __shfl_xor(hm, 32, 64));
    return hm;
}

__device__ __forceinline__ void pack_p(const float e[16], bf16x8& a0, bf16x8& a1) {
    int4 p0, p1;
    p0.x = __builtin_amdgcn_perm(__float_as_uint(e[1]),  __float_as_uint(e[0]),  0x07060302u);
    p0.y = __builtin_amdgcn_perm(__float_as_uint(e[3]),  __float_as_uint(e[2]),  0x07060302u);
    p0.z = __builtin_amdgcn_perm(__float_as_uint(e[5]),  __float_as_uint(e[4]),  0x07060302u);
    p0.w = __builtin_amdgcn_perm(__float_as_uint(e[7]),  __float_as_uint(e[6]),  0x07060302u);
    p1.x = __builtin_amdgcn_perm(__float_as_uint(e[9]),  __float_as_uint(e[8]),  0x07060302u);
    p1.y = __builtin_amdgcn_perm(__float_as_uint(e[11]), __float_as_uint(e[10]), 0x07060302u);
    p1.z = __builtin_amdgcn_perm(__float_as_uint(e[13]), __float_as_uint(e[12]), 0x07060302u);
    p1.w = __builtin_amdgcn_perm(__float_as_uint(e[15]), __float_as_uint(e[14]), 0x07060302u);
    a0 = *(bf16x8*)&p0;
    a1 = *(bf16x8*)&p1;
}

// ---------------------------------------------------------------------------
// Prep (R10-proven): softmax -> frag-swizzled bf16, 4 lanes/row; leaf
// coeffs; x transpose/gather (restored — R12 proved its removal is null,
// and xT gives coalesced coop<0> x reads); schedule build.
// ---------------------------------------------------------------------------
__global__ __launch_bounds__(256) void prep_kernel(
    const float* __restrict__ w1, const float* __restrict__ w2,
    const float* __restrict__ w3, const float* __restrict__ w4,
    const float* __restrict__ w5, const float* __restrict__ w6,
    const float* __restrict__ w7, const float* __restrict__ w8,
    const float* __restrict__ mu, const float* __restrict__ ls,
    const float* __restrict__ x,  const int* __restrict__ scope,
    const int* __restrict__ f1, const int* __restrict__ f2,
    const int* __restrict__ f3, const int* __restrict__ f4,
    const int* __restrict__ f5, const int* __restrict__ f6,
    const int* __restrict__ f7, const int* __restrict__ f8,
    char* __restrict__ ws)
{
    const int bx = blockIdx.x, t = threadIdx.x;
    if (bx < 255) {
        const int g = bx;
        const float* src;
        if (g < 128)      src = w1 + g * 4096;
        else if (g < 192) src = w2 + (g - 128) * 4096;
        else if (g < 224) src = w3 + (g - 192) * 4096;
        else if (g < 240) src = w4 + (g - 224) * 4096;
        else if (g < 248) src = w5 + (g - 240) * 4096;
        else if (g < 252) src = w6 + (g - 248) * 4096;
        else              src = (g < 254) ? (w7 + (g - 252) * 4096) : w8;

        const int row = t >> 2;      // 0..63 (j)
        const int sub = t & 3;       // k-quarter, 4 lanes per row
        const float* rp = src + row * 64 + sub * 16;
        float4 v0 = *(const float4*)rp;
        float4 v1 = *(const float4*)(rp + 4);
        float4 v2 = *(const float4*)(rp + 8);
        float4 v3 = *(const float4*)(rp + 12);
        float v[16] = { v0.x, v0.y, v0.z, v0.w,  v1.x, v1.y, v1.z, v1.w,
                        v2.x, v2.y, v2.z, v2.w,  v3.x, v3.y, v3.z, v3.w };
        float mx = fmaxf(fmaxf(fmaxf(fmaxf(v[0], v[1]), fmaxf(v[2], v[3])),
                               fmaxf(fmaxf(v[4], v[5]), fmaxf(v[6], v[7]))),
                         fmaxf(fmaxf(fmaxf(v[8], v[9]), fmaxf(v[10], v[11])),
                               fmaxf(fmaxf(v[12], v[13]), fmaxf(v[14], v[15]))));
        mx = fmaxf(mx, __shfl_xor(mx, 1, 64));
        mx = fmaxf(mx, __shfl_xor(mx, 2, 64));
        float e[16], sm = 0.f;
        #pragma unroll
        for (int i = 0; i < 16; ++i) { e[i] = __expf(v[i] - mx); sm += e[i]; }
        sm += __shfl_xor(sm, 1, 64);
        sm += __shfl_xor(sm, 2, 64);
        const float inv = 1.0f / sm;    // one division per thread (was 16)

        unsigned short* dst = (unsigned short*)(ws + WS_WBJ) + g * 4096;
        #pragma unroll
        for (int c = 0; c < 2; ++c) {
            const int tc = 2 * sub + c;          // (k>>3) of this 8-chunk
            const int f  = ((row >> 4) << 1) | (tc >> 2);
            const int ln = ((tc & 3) << 4) | (row & 15);
            int4 pk;
            pk.x = (int)pk2(e[c*8+0] * inv, e[c*8+1] * inv);
            pk.y = (int)pk2(e[c*8+2] * inv, e[c*8+3] * inv);
            pk.z = (int)pk2(e[c*8+4] * inv, e[c*8+5] * inv);
            pk.w = (int)pk2(e[c*8+6] * inv, e[c*8+7] * inv);
            *(int4*)(dst + (size_t)(f * 64 + ln) * 8) = pk;   // 16B aligned
        }
    } else if (bx < 319) {
        const int idx = (bx - 255) * 256 + t;
        float m = mu[idx], l = ls[idx];
        float is2 = __expf(-2.0f * l);
        ((float*)(ws + WS_A))[idx] = -0.5f * is2 * INV_LN2_F;
        ((float*)(ws + WS_B))[idx] = m * is2 * INV_LN2_F;
        ((float*)(ws + WS_C))[idx] = (-0.5f * m * m * is2 - l - LOG2PI_F) * INV_LN2_F;
    } else if (bx < 575) {
        const int bb = bx - 319;
        const int sd = scope[t];
        float* xT = (float*)(ws + WS_XT);
        #pragma unroll
        for (int i = 0; i < 8; ++i) {
            int b = bb * 8 + i;
            xT[t * 2048 + b] = x[b * 256 + sd];
        }
    } else {
        __shared__ int sf[512];
        for (int i = t; i < 256; i += 256) sf[i]        = f1[i];
        for (int i = t; i < 128; i += 256) sf[256 + i]  = f2[i];
        for (int i = t; i <  64; i += 256) sf[384 + i]  = f3[i];
        for (int i = t; i <  32; i += 256) sf[448 + i]  = f4[i];
        for (int i = t; i <  16; i += 256) sf[480 + i]  = f5[i];
        for (int i = t; i <   8; i += 256) sf[496 + i]  = f6[i];
        for (int i = t; i <   4; i += 256) sf[504 + i]  = f7[i];
        for (int i = t; i <   2; i += 256) sf[508 + i]  = f8[i];
        __syncthreads();
        const int* F1 = &sf[0];   const int* F2 = &sf[256];
        const int* F3 = &sf[384]; const int* F4 = &sf[448];
        const int* F5 = &sf[480]; const int* F6 = &sf[496];
        const int* F7 = &sf[504]; const int* F8 = &sf[508];
        Op* base = (Op*)(ws + WS_SCHED);
        if (t < 16) {
            Op* o = base + t * 15;
            int r0 = F4[2*t], r1 = F4[2*t+1];
            int P[4] = { F3[2*r0], F3[2*r0+1], F3[2*r1], F3[2*r1+1] };
            #pragma unroll
            for (int j = 0; j < 4; ++j) {
                int L0 = F2[2*P[j]], L1 = F2[2*P[j]+1];
                o[2*j]   = { L0 * 4096, F1[2*L0], F1[2*L0+1], 0 };
                o[2*j+1] = { L1 * 4096, F1[2*L1], F1[2*L1+1], 0 };
                o[8+j]   = { (128 + P[j]) * 4096, 0, 0, 0 };
            }
            o[12] = { (192 + r0) * 4096, 0, 0, 0 };
            o[13] = { (192 + r1) * 4096, 0, 0, 0 };
            o[14] = { (224 + t)  * 4096, 0, 0, 0 };
        } else if (t == 16) {
            Op* o = base + 240;
            int g[4] = { F7[2*F8[0]], F7[2*F8[0]+1], F7[2*F8[1]], F7[2*F8[1]+1] };
            #pragma unroll
            for (int a = 0; a < 4; ++a) {
                int l0 = F6[2*g[a]], l1 = F6[2*g[a]+1];
                o[2*a]   = { (240 + l0) * 4096, F5[2*l0], F5[2*l0+1], 0 };
                o[2*a+1] = { (240 + l1) * 4096, F5[2*l1], F5[2*l1+1], 0 };
                o[8+a]   = { (248 + g[a]) * 4096, 0, 0, 0 };
            }
            o[12] = { (252 + F8[0]) * 4096, 0, 0, 0 };
            o[13] = { (252 + F8[1]) * 4096, 0, 0, 0 };
            o[14] = { 254 * 4096, 0, 0, 0 };
        }
    }
}

// ---------------------------------------------------------------------------
// Per-op helpers (linear-domain values with per-row pow2 scale M)
// ---------------------------------------------------------------------------
__device__ __forceinline__ void load_bfrag(const unsigned short* __restrict__ wbJ,
                                           int w, int lane, int4 bf[8]) {
    const int4* wp = (const int4*)(wbJ + w);
    #pragma unroll
    for (int f = 0; f < 8; ++f) bf[f] = wp[f * 64 + lane];   // coalesced 1KB/load
}

// Exact pow2 renorm at EVERY level (R1 lesson: skip-norm is unsafe).
__device__ __forceinline__ void prod_norm(const float av[16], const float bv[16],
                                          float MA, float MB,
                                          float p[16], float& Mrow) {
    float pv[16];
    #pragma unroll
    for (int i = 0; i < 16; ++i) pv[i] = av[i] * bv[i];
    const float rm = rmax16(pv);
    const int e = (int)((__float_as_uint(rm) >> 23) & 0xFF) - 127;
    #pragma unroll
    for (int i = 0; i < 16; ++i) p[i] = ldexpf(pv[i], -e);   // exact scaling
    Mrow = MA + MB + (float)e;
}

// rowStart = absolute batch row of this lane-group's m=0 (xT: coalesced)
__device__ __forceinline__ void gauss_p(const Op& op,
    const float* __restrict__ xT, const float* __restrict__ Ag,
    const float* __restrict__ Bg, const float* __restrict__ Cg,
    int rowStart, int m, int q, float p[16], float& Mrow)
{
    const int d0 = op.c0, d1 = op.c1;
    const float xv0 = xT[d0 * 2048 + rowStart + m];
    const float xv1 = xT[d1 * 2048 + rowStart + m];
    const float x0s = xv0 * xv0, x1s = xv1 * xv1;
    float hv[16];
    #pragma unroll
    for (int kh = 0; kh < 2; ++kh) {
        const int kb = kh * 32 + q * 8;
        F8v A0 = ld8(Ag + d0*64 + kb), B0 = ld8(Bg + d0*64 + kb);
        F8v C0 = ld8(Cg + d0*64 + kb);
        F8v A1 = ld8(Ag + d1*64 + kb), B1 = ld8(Bg + d1*64 + kb);
        F8v C1 = ld8(Cg + d1*64 + kb);
        #pragma unroll
        for (int i = 0; i < 8; ++i) {
            float t0 = fmaf(A0.v[i], x0s, C0.v[i]);
            t0 = fmaf(B0.v[i], xv0, t0);
            float t1 = fmaf(A1.v[i], x1s, C1.v[i]);
            t1 = fmaf(B1.v[i], xv1, t1);
            hv[kh*8+i] = t0 + t1;
        }
    }
    const float hm = rmax16(hv);
    #pragma unroll
    for (int i = 0; i < 16; ++i) p[i] = __builtin_amdgcn_exp2f(hv[i] - hm);
    Mrow = hm;
}

__device__ __forceinline__ void gprod_p(const Op& op,
    const unsigned short* __restrict__ inAcc, const float* __restrict__ inM,
    int rowStart, int m, int q, float p[16], float& Mrow)
{
    const int4* A4 = (const int4*)(inAcc + (size_t)(op.c0 * 2048 + rowStart + m) * 64);
    const int4* B4 = (const int4*)(inAcc + (size_t)(op.c1 * 2048 + rowStart + m) * 64);
    float av[16], bv[16];
    up8(A4[q], av); up8(A4[4+q], av + 8);
    up8(B4[q], bv); up8(B4[4+q], bv + 8);
    prod_norm(av, bv, inM[op.c0 * 2048 + rowStart + m],
              inM[op.c1 * 2048 + rowStart + m], p, Mrow);
}

// rowBase = 0 or 16 within the 32-row tile
__device__ __forceinline__ void slot_prod(const unsigned short* slotS, const float* Mslot,
                                          int sA, int sB, int rowBase, int m, int q,
                                          float p[16], float& Mrow)
{
    const int4* A4 = (const int4*)(slotS + sA * 32 * SROW + (rowBase + m) * SROW);
    const int4* B4 = (const int4*)(slotS + sB * 32 * SROW + (rowBase + m) * SROW);
    float av[16], bv[16];
    up8(A4[q], av); up8(A4[4+q], av + 8);
    up8(B4[q], bv); up8(B4[4+q], bv + 8);
    prod_norm(av, bv, Mslot[sA * 32 + rowBase + m],
              Mslot[sB * 32 + rowBase + m], p, Mrow);
}

__device__ __forceinline__ void mfma8(const float p[16], const int4 bf[8], f32x4 acc[4]) {
    bf16x8 a0, a1;
    pack_p(p, a0, a1);
    #pragma unroll
    for (int jt = 0; jt < 4; ++jt) {
        f32x4 z = {0.f, 0.f, 0.f, 0.f};
        z = __builtin_amdgcn_mfma_f32_16x16x32_bf16(a0, *(bf16x8*)&bf[jt*2+0], z, 0, 0, 0);
        z = __builtin_amdgcn_mfma_f32_16x16x32_bf16(a1, *(bf16x8*)&bf[jt*2+1], z, 0, 0, 0);
        acc[jt] = z;
    }
}

__device__ __forceinline__ void store_slot(unsigned short* slotS, float* Mslot,
                                           int sl, int rowBase, const f32x4 acc[4],
                                           float Mrow, int m, int q)
{
    unsigned short* S = slotS + sl * 32 * SROW;
    #pragma unroll
    for (int jt = 0; jt < 4; ++jt)
        #pragma unroll
        for (int r = 0; r < 4; ++r)
            S[(rowBase + q*4 + r) * SROW + jt*16 + m] = (unsigned short)bfr(acc[jt][r]);
    if (q == 0) Mslot[sl * 32 + rowBase + m] = Mrow;
}

__device__ __forceinline__ void wave_fence() {
    __builtin_amdgcn_wave_barrier();
    __builtin_amdgcn_s_waitcnt(0xC07F);   // lgkmcnt(0)
    __builtin_amdgcn_wave_barrier();
}

// Mix compute using PRE-LOADED weight fragments (R8-proven prefetch).
// NH=2: both 16-row halves ILP-paired (R3-proven). NH=1: single half.
template<int NH>
__device__ __forceinline__ void mix_core(const int4 bf[8],
    unsigned short* slotS, float* Mslot,
    int sA, int sB, int sD, int m, int q)
{
    if constexpr (NH == 2) {
        float p0[16], p1[16], M0, M1;
        slot_prod(slotS, Mslot, sA, sB, 0,  m, q, p0, M0);
        slot_prod(slotS, Mslot, sA, sB, 16, m, q, p1, M1);
        f32x4 acc0[4], acc1[4];
        mfma8(p0, bf, acc0);
        mfma8(p1, bf, acc1);
        store_slot(slotS, Mslot, sD, 0,  acc0, M0, m, q);
        store_slot(slotS, Mslot, sD, 16, acc1, M1, m, q);
    } else {
        float p[16], M;
        slot_prod(slotS, Mslot, sA, sB, 0, m, q, p, M);
        f32x4 acc[4];
        mfma8(p, bf, acc);
        store_slot(slotS, Mslot, sD, 0, acc, M, m, q);
    }
}

// ---------------------------------------------------------------------------
// 4-wave cooperative tree kernel — R8/R10 structure (dual-half ILP, weight
// prefetch, unclamped bounds).
// R13: 2D XCD SWIZZLE (trees x tiles). Fetch accounting: per-XCD traffic =
// T*0.125MB (weights) + (128/T)*32KB (xT rows); R10's T=2 gave 2+16=18MB
// (x duplicated to all 8 XCDs). T=4 minimizes: XCD pair {2j,2j+1} owns trees
// [4j,4j+4); XCD 2j takes tiles 0-31, 2j+1 takes tiles 32-63. Per-XCD:
// 0.5MB weights + 1024 xT rows (~0.25MB coalesced) -> ~12MB total fetch.
// Bijective: 1024 = 8 XCD x 4 trees x 32 tiles.
//   wave w: leaves 2w,2w+1 -> slots 2w,2w+1 ; L2 mix w: 2w,2w+1 -> 2w
//   L3 u (waves 0,2): 4u,4u+2 -> 4u ; root (wave 0): 0,4
// MODE 0 (K14, levels 1-4): 32-row tiles dual-half -> L4 acc+M.
// MODE 1 (tail, levels 5-8): 16-row tiles single-half -> d_out.
// ---------------------------------------------------------------------------
template<int MODE>
__global__ __launch_bounds__(256) void circuit_coop(
    const unsigned short* __restrict__ wbJ,
    const Op* __restrict__ schedG, int ntile,
    const float* __restrict__ xT, const float* __restrict__ Ag,
    const float* __restrict__ Bg, const float* __restrict__ Cg,
    const unsigned short* __restrict__ inAcc, const float* __restrict__ inM,
    unsigned short* __restrict__ outAcc, float* __restrict__ outM,
    float* __restrict__ outLog)
{
    constexpr int NH = (MODE == 0) ? 2 : 1;
    __shared__ __align__(16) unsigned short slotS[8 * 32 * SROW];  // 36.9 KB
    __shared__ float Mslot[8 * 32];
    __shared__ Op ops[16];

    const int t    = threadIdx.x;
    const int wv   = t >> 6;
    const int lane = t & 63;
    const int m    = lane & 15;
    const int q    = lane >> 4;
    int s, b0;
    if constexpr (MODE == 0) {
        // R13 2D XCD swizzle: XCD k=blockIdx&7; pair j=k>>1 owns trees
        // [4j,4j+4); half=k&1 selects tile range. Bijective over 1024.
        const int xcd  = blockIdx.x & 7;
        const int idx  = blockIdx.x >> 3;         // 0..127
        const int j    = xcd >> 1, half = xcd & 1;
        s  = 4 * j + (idx >> 5);                  // tree 0..15
        b0 = (((half << 5) | (idx & 31))) * 32;   // tile row base
    } else {
        s  = blockIdx.x / ntile;
        b0 = (blockIdx.x % ntile) * 16;
    }

    if (t < 15) *(int4*)&ops[t] = ((const int4*)(schedG + s * 15))[t];
    __syncthreads();

    // ---- prefetch: phase-2 weights issued NOW, drain under phase 1
    int4 bf2[8];
    load_bfrag(wbJ, ops[8 + wv].w, lane, bf2);

    // ---- phase 1: 2 leaves per wave
    #pragma unroll
    for (int i = 0; i < 2; ++i) {
        const int sl = 2 * wv + i;
        const Op op = ops[sl];
        int4 bf[8];
        load_bfrag(wbJ, op.w, lane, bf);
        if constexpr (NH == 2) {
            float p0[16], p1[16], M0, M1;
            if (MODE == 0) {
                gauss_p(op, xT, Ag, Bg, Cg, b0,      m, q, p0, M0);
                gauss_p(op, xT, Ag, Bg, Cg, b0 + 16, m, q, p1, M1);
            } else {
                gprod_p(op, inAcc, inM, b0,      m, q, p0, M0);
                gprod_p(op, inAcc, inM, b0 + 16, m, q, p1, M1);
            }
            f32x4 acc0[4], acc1[4];
            mfma8(p0, bf, acc0);
            mfma8(p1, bf, acc1);
            store_slot(slotS, Mslot, sl, 0,  acc0, M0, m, q);
            store_slot(slotS, Mslot, sl, 16, acc1, M1, m, q);
        } else {
            float p[16], M;
            if (MODE == 0) gauss_p(op, xT, Ag, Bg, Cg, b0, m, q, p, M);
            else           gprod_p(op, inAcc, inM, b0, m, q, p, M);
            f32x4 acc[4];
            mfma8(p, bf, acc);
            store_slot(slotS, Mslot, sl, 0, acc, M, m, q);
        }
    }
    wave_fence();

    // ---- prefetch: phase-3 weights (waves 0,2) before phase-2 compute
    const int u = wv >> 1;
    int4 bf3[8];
    if ((wv & 1) == 0) load_bfrag(wbJ, ops[12 + u].w, lane, bf3);

    // ---- phase 2: L2 mix j = wv, reads own slots 2j,2j+1 -> 2j
    mix_core<NH>(bf2, slotS, Mslot, 2*wv, 2*wv + 1, 2*wv, m, q);
    __syncthreads();

    // ---- phase 3: L3 mix u on waves 0,2 (wave 0 prefetches root weights)
    int4 bf4[8];
    if ((wv & 1) == 0) {
        if (wv == 0) load_bfrag(wbJ, ops[14].w, lane, bf4);
        mix_core<NH>(bf3, slotS, Mslot, 4*u, 4*u + 2, 4*u, m, q);
    }
    __syncthreads();

    // ---- phase 4: root (wave 0): reads slots 0,4 with preloaded bf4
    if (wv == 0) {
        if constexpr (NH == 2) {   // MODE 0 epilogue: L4 acc+M
            float p0[16], p1[16], M0, M1;
            slot_prod(slotS, Mslot, 0, 4, 0,  m, q, p0, M0);
            slot_prod(slotS, Mslot, 0, 4, 16, m, q, p1, M1);
            f32x4 acc0[4], acc1[4];
            mfma8(p0, bf4, acc0);
            mfma8(p1, bf4, acc1);
            const int rowOff = s * 2048 + b0;
            #pragma unroll
            for (int jt = 0; jt < 4; ++jt)
                #pragma unroll
                for (int r = 0; r < 4; ++r) {
                    outAcc[(size_t)(rowOff +      q*4 + r) * 64 + jt*16 + m] =
                        (unsigned short)bfr(acc0[jt][r]);
                    outAcc[(size_t)(rowOff + 16 + q*4 + r) * 64 + jt*16 + m] =
                        (unsigned short)bfr(acc1[jt][r]);
                }
            if (q == 0) {
                outM[rowOff + m]      = M0;
                outM[rowOff + 16 + m] = M1;
            }
        } else {                    // MODE 1 epilogue: final natural-log output
            float p0[16], M0;
            slot_prod(slotS, Mslot, 0, 4, 0, m, q, p0, M0);
            f32x4 acc0[4];
            mfma8(p0, bf4, acc0);
            float mr0[4];
            #pragma unroll
            for (int r = 0; r < 4; ++r) mr0[r] = __shfl(M0, q * 4 + r, 64);
            #pragma unroll
            for (int jt = 0; jt < 4; ++jt)
                #pragma unroll
                for (int r = 0; r < 4; ++r)
                    outLog[(b0 + q*4 + r) * 64 + jt*16 + m] =
                        (__builtin_amdgcn_logf(acc0[jt][r]) + mr0[r]) * LN2_F;
        }
    }
}

// ---------------------------------------------------------------------------
// d_in order: 0:x 1:mu 2:log_sigma 3:in_scope_idx, then fold_idx{l}, w{l}
// ---------------------------------------------------------------------------
extern "C" void kernel_launch(void* const* d_in, const int* in_sizes, int n_in,
                              void* d_out, int out_size, void* d_ws, size_t ws_size,
                              hipStream_t stream) {
    const float* x     = (const float*)d_in[0];
    const float* mu    = (const float*)d_in[1];
    const float* lsg   = (const float*)d_in[2];
    const int*   scope = (const int*)d_in[3];
    const int*   f1 = (const int*)d_in[4];   const float* w1 = (const float*)d_in[5];
    const int*   f2 = (const int*)d_in[6];   const float* w2 = (const float*)d_in[7];
    const int*   f3 = (const int*)d_in[8];   const float* w3 = (const float*)d_in[9];
    const int*   f4 = (const int*)d_in[10];  const float* w4 = (const float*)d_in[11];
    const int*   f5 = (const int*)d_in[12];  const float* w5 = (const float*)d_in[13];
    const int*   f6 = (const int*)d_in[14];  const float* w6 = (const float*)d_in[15];
    const int*   f7 = (const int*)d_in[16];  const float* w7 = (const float*)d_in[17];
    const int*   f8 = (const int*)d_in[18];  const float* w8 = (const float*)d_in[19];

    char* ws = (char*)d_ws;
    const unsigned short* wbJ = (const unsigned short*)(ws + WS_WBJ);
    const float* Ag  = (const float*)(ws + WS_A);
    const float* Bg  = (const float*)(ws + WS_B);
    const float* Cg  = (const float*)(ws + WS_C);
    const float* xT  = (const float*)(ws + WS_XT);
    const Op*    sch = (const Op*)(ws + WS_SCHED);
    unsigned short* L4A = (unsigned short*)(ws + WS_L4A);
    float*          L4M = (float*)(ws + WS_L4M);

    prep_kernel<<<576, 256, 0, stream>>>(w1, w2, w3, w4, w5, w6, w7, w8,
                                         mu, lsg, x, scope,
                                         f1, f2, f3, f4, f5, f6, f7, f8, ws);

    // levels 1..4: 16 trees x 64 tiles of 32 rows, 4-wave cooperative trees
    circuit_coop<0><<<1024, 256, 0, stream>>>(
        wbJ, sch, 64,
        xT, Ag, Bg, Cg,
        nullptr, nullptr,
        L4A, L4M, nullptr);

    // levels 5..8: 128 tiles of 16 rows
    circuit_coop<1><<<128, 256, 0, stream>>>(
        wbJ, sch + 240, 128,
        nullptr, nullptr, nullptr, nullptr,
        L4A, L4M,
        nullptr, nullptr, (float*)d_out);
}

// Round 14
// 127.688 us; speedup vs baseline: 1.0196x; 1.0196x over previous
//
#include <hip/hip_runtime.h>
#include <math.h>

#define LOG2PI_F  0.9189385332046727f
#define INV_LN2_F 1.4426950408889634f
#define LN2_F     0.6931471805599453f
#define SROW      72          // slot row stride in shorts (144B, 16B-aligned rows)

typedef short bf16x8 __attribute__((ext_vector_type(8)));
typedef float f32x4  __attribute__((ext_vector_type(4)));

struct __align__(16) Op { int w; int c0; int c1; int pad; };

// ---- workspace byte offsets -------------------------------------------------
#define WS_WBJ   0u          // bf16[255][8 frag][64 lane][8] pre-swizzled weights
#define WS_A     2097152u    // float[256*64]  leaf coeff A (log2 domain)
#define WS_B     2162688u    // float[256*64]  leaf coeff B
#define WS_C     2228224u    // float[256*64]  leaf coeff C
#define WS_XT    2293760u    // float[256*2048] x gathered+transposed: xT[d][b]
#define WS_SCHED 4390912u    // Op[16*15 @0 .. K14 trees, 15 @240 .. tail L5-8]
#define WS_L4A   4395008u    // bf16[16*2048*64] level-4 acc values
#define WS_L4M   8589312u    // float[16*2048]   level-4 row scales (log2)

// All f32->bf16 conversions use the proven integer-RNE path (R2 lesson:
// v_cvt_pk_bf16_f32 inline asm produced NaN poison on this toolchain).
__device__ __forceinline__ short bfr(float f) {   // f32 -> bf16 RNE
    unsigned int u = __float_as_uint(f);
    u += 0x7fffu + ((u >> 16) & 1u);
    return (short)(u >> 16);
}

__device__ __forceinline__ unsigned pk2(float a, float b) {  // lo=bf16(a) hi=bf16(b)
    return (unsigned)(unsigned short)bfr(a) | ((unsigned)(unsigned short)bfr(b) << 16);
}

struct F8v { float v[8]; };
__device__ __forceinline__ F8v ld8(const float* p) {
    F8v r;
    float4 a = *(const float4*)p;
    float4 b = *(const float4*)(p + 4);
    r.v[0]=a.x; r.v[1]=a.y; r.v[2]=a.z; r.v[3]=a.w;
    r.v[4]=b.x; r.v[5]=b.y; r.v[6]=b.z; r.v[7]=b.w;
    return r;
}

__device__ __forceinline__ void up8(int4 v, float* o) {   // 8 bf16 -> f32
    o[0] = __uint_as_float(((unsigned)v.x) << 16);
    o[1] = __uint_as_float(((unsigned)v.x) & 0xffff0000u);
    o[2] = __uint_as_float(((unsigned)v.y) << 16);
    o[3] = __uint_as_float(((unsigned)v.y) & 0xffff0000u);
    o[4] = __uint_as_float(((unsigned)v.z) << 16);
    o[5] = __uint_as_float(((unsigned)v.z) & 0xffff0000u);
    o[6] = __uint_as_float(((unsigned)v.w) << 16);
    o[7] = __uint_as_float(((unsigned)v.w) & 0xffff0000u);
}

__device__ __forceinline__ float rmax16(const float hv[16]) {
    float m01 = fmaxf(hv[0], hv[1]),  m23 = fmaxf(hv[2], hv[3]);
    float m45 = fmaxf(hv[4], hv[5]),  m67 = fmaxf(hv[6], hv[7]);
    float m89 = fmaxf(hv[8], hv[9]),  mab = fmaxf(hv[10], hv[11]);
    float mcd = fmaxf(hv[12], hv[13]), mef = fmaxf(hv[14], hv[15]);
    float hm = fmaxf(fmaxf(fmaxf(m01, m23), fmaxf(m45, m67)),
                     fmaxf(fmaxf(m89, mab), fmaxf(mcd, mef)));
    hm = fmaxf(hm, __shfl_xor(hm, 16, 64));
    hm = fmaxf(hm, __shfl_xor(hm, 32, 64));
    return hm;
}

__device__ __forceinline__ void pack_p(const float e[16], bf16x8& a0, bf16x8& a1) {
    int4 p0, p1;
    p0.x = __builtin_amdgcn_perm(__float_as_uint(e[1]),  __float_as_uint(e[0]),  0x07060302u);
    p0.y = __builtin_amdgcn_perm(__float_as_uint(e[3]),  __float_as_uint(e[2]),  0x07060302u);
    p0.z = __builtin_amdgcn_perm(__float_as_uint(e[5]),  __float_as_uint(e[4]),  0x07060302u);
    p0.w = __builtin_amdgcn_perm(__float_as_uint(e[7]),  __float_as_uint(e[6]),  0x07060302u);
    p1.x = __builtin_amdgcn_perm(__float_as_uint(e[9]),  __float_as_uint(e[8]),  0x07060302u);
    p1.y = __builtin_amdgcn_perm(__float_as_uint(e[11]), __float_as_uint(e[10]), 0x07060302u);
    p1.z = __builtin_amdgcn_perm(__float_as_uint(e[13]), __float_as_uint(e[12]), 0x07060302u);
    p1.w = __builtin_amdgcn_perm(__float_as_uint(e[15]), __float_as_uint(e[14]), 0x07060302u);
    a0 = *(bf16x8*)&p0;
    a1 = *(bf16x8*)&p1;
}

// ---------------------------------------------------------------------------
// Prep (proven in R3): softmax -> frag-swizzled bf16, 4 lanes/row; leaf
// coeffs; x transpose/gather; schedule build.
// ---------------------------------------------------------------------------
__global__ __launch_bounds__(256) void prep_kernel(
    const float* __restrict__ w1, const float* __restrict__ w2,
    const float* __restrict__ w3, const float* __restrict__ w4,
    const float* __restrict__ w5, const float* __restrict__ w6,
    const float* __restrict__ w7, const float* __restrict__ w8,
    const float* __restrict__ mu, const float* __restrict__ ls,
    const float* __restrict__ x,  const int* __restrict__ scope,
    const int* __restrict__ f1, const int* __restrict__ f2,
    const int* __restrict__ f3, const int* __restrict__ f4,
    const int* __restrict__ f5, const int* __restrict__ f6,
    const int* __restrict__ f7, const int* __restrict__ f8,
    char* __restrict__ ws)
{
    const int bx = blockIdx.x, t = threadIdx.x;
    if (bx < 255) {
        const int g = bx;
        const float* src;
        if (g < 128)      src = w1 + g * 4096;
        else if (g < 192) src = w2 + (g - 128) * 4096;
        else if (g < 224) src = w3 + (g - 192) * 4096;
        else if (g < 240) src = w4 + (g - 224) * 4096;
        else if (g < 248) src = w5 + (g - 240) * 4096;
        else if (g < 252) src = w6 + (g - 248) * 4096;
        else              src = (g < 254) ? (w7 + (g - 252) * 4096) : w8;

        const int row = t >> 2;      // 0..63 (j)
        const int sub = t & 3;       // k-quarter, 4 lanes per row
        const float* rp = src + row * 64 + sub * 16;
        float4 v0 = *(const float4*)rp;
        float4 v1 = *(const float4*)(rp + 4);
        float4 v2 = *(const float4*)(rp + 8);
        float4 v3 = *(const float4*)(rp + 12);
        float v[16] = { v0.x, v0.y, v0.z, v0.w,  v1.x, v1.y, v1.z, v1.w,
                        v2.x, v2.y, v2.z, v2.w,  v3.x, v3.y, v3.z, v3.w };
        float mx = fmaxf(fmaxf(fmaxf(fmaxf(v[0], v[1]), fmaxf(v[2], v[3])),
                               fmaxf(fmaxf(v[4], v[5]), fmaxf(v[6], v[7]))),
                         fmaxf(fmaxf(fmaxf(v[8], v[9]), fmaxf(v[10], v[11])),
                               fmaxf(fmaxf(v[12], v[13]), fmaxf(v[14], v[15]))));
        mx = fmaxf(mx, __shfl_xor(mx, 1, 64));
        mx = fmaxf(mx, __shfl_xor(mx, 2, 64));
        float e[16], sm = 0.f;
        #pragma unroll
        for (int i = 0; i < 16; ++i) { e[i] = __expf(v[i] - mx); sm += e[i]; }
        sm += __shfl_xor(sm, 1, 64);
        sm += __shfl_xor(sm, 2, 64);
        const float inv = 1.0f / sm;    // one division per thread (was 16)

        unsigned short* dst = (unsigned short*)(ws + WS_WBJ) + g * 4096;
        #pragma unroll
        for (int c = 0; c < 2; ++c) {
            const int tc = 2 * sub + c;          // (k>>3) of this 8-chunk
            const int f  = ((row >> 4) << 1) | (tc >> 2);
            const int ln = ((tc & 3) << 4) | (row & 15);
            int4 pk;
            pk.x = (int)pk2(e[c*8+0] * inv, e[c*8+1] * inv);
            pk.y = (int)pk2(e[c*8+2] * inv, e[c*8+3] * inv);
            pk.z = (int)pk2(e[c*8+4] * inv, e[c*8+5] * inv);
            pk.w = (int)pk2(e[c*8+6] * inv, e[c*8+7] * inv);
            *(int4*)(dst + (size_t)(f * 64 + ln) * 8) = pk;   // 16B aligned
        }
    } else if (bx < 319) {
        const int idx = (bx - 255) * 256 + t;
        float m = mu[idx], l = ls[idx];
        float is2 = __expf(-2.0f * l);
        ((float*)(ws + WS_A))[idx] = -0.5f * is2 * INV_LN2_F;
        ((float*)(ws + WS_B))[idx] = m * is2 * INV_LN2_F;
        ((float*)(ws + WS_C))[idx] = (-0.5f * m * m * is2 - l - LOG2PI_F) * INV_LN2_F;
    } else if (bx < 575) {
        const int bb = bx - 319;
        const int sd = scope[t];
        float* xT = (float*)(ws + WS_XT);
        #pragma unroll
        for (int i = 0; i < 8; ++i) {
            int b = bb * 8 + i;
            xT[t * 2048 + b] = x[b * 256 + sd];
        }
    } else {
        __shared__ int sf[512];
        for (int i = t; i < 256; i += 256) sf[i]        = f1[i];
        for (int i = t; i < 128; i += 256) sf[256 + i]  = f2[i];
        for (int i = t; i <  64; i += 256) sf[384 + i]  = f3[i];
        for (int i = t; i <  32; i += 256) sf[448 + i]  = f4[i];
        for (int i = t; i <  16; i += 256) sf[480 + i]  = f5[i];
        for (int i = t; i <   8; i += 256) sf[496 + i]  = f6[i];
        for (int i = t; i <   4; i += 256) sf[504 + i]  = f7[i];
        for (int i = t; i <   2; i += 256) sf[508 + i]  = f8[i];
        __syncthreads();
        const int* F1 = &sf[0];   const int* F2 = &sf[256];
        const int* F3 = &sf[384]; const int* F4 = &sf[448];
        const int* F5 = &sf[480]; const int* F6 = &sf[496];
        const int* F7 = &sf[504]; const int* F8 = &sf[508];
        Op* base = (Op*)(ws + WS_SCHED);
        if (t < 16) {
            Op* o = base + t * 15;
            int r0 = F4[2*t], r1 = F4[2*t+1];
            int P[4] = { F3[2*r0], F3[2*r0+1], F3[2*r1], F3[2*r1+1] };
            #pragma unroll
            for (int j = 0; j < 4; ++j) {
                int L0 = F2[2*P[j]], L1 = F2[2*P[j]+1];
                o[2*j]   = { L0 * 4096, F1[2*L0], F1[2*L0+1], 0 };
                o[2*j+1] = { L1 * 4096, F1[2*L1], F1[2*L1+1], 0 };
                o[8+j]   = { (128 + P[j]) * 4096, 0, 0, 0 };
            }
            o[12] = { (192 + r0) * 4096, 0, 0, 0 };
            o[13] = { (192 + r1) * 4096, 0, 0, 0 };
            o[14] = { (224 + t)  * 4096, 0, 0, 0 };
        } else if (t == 16) {
            Op* o = base + 240;
            int g[4] = { F7[2*F8[0]], F7[2*F8[0]+1], F7[2*F8[1]], F7[2*F8[1]+1] };
            #pragma unroll
            for (int a = 0; a < 4; ++a) {
                int l0 = F6[2*g[a]], l1 = F6[2*g[a]+1];
                o[2*a]   = { (240 + l0) * 4096, F5[2*l0], F5[2*l0+1], 0 };
                o[2*a+1] = { (240 + l1) * 4096, F5[2*l1], F5[2*l1+1], 0 };
                o[8+a]   = { (248 + g[a]) * 4096, 0, 0, 0 };
            }
            o[12] = { (252 + F8[0]) * 4096, 0, 0, 0 };
            o[13] = { (252 + F8[1]) * 4096, 0, 0, 0 };
            o[14] = { 254 * 4096, 0, 0, 0 };
        }
    }
}

// ---------------------------------------------------------------------------
// Per-op helpers (linear-domain values with per-row pow2 scale M)
// ---------------------------------------------------------------------------
__device__ __forceinline__ void load_bfrag(const unsigned short* __restrict__ wbJ,
                                           int w, int lane, int4 bf[8]) {
    const int4* wp = (const int4*)(wbJ + w);
    #pragma unroll
    for (int f = 0; f < 8; ++f) bf[f] = wp[f * 64 + lane];   // coalesced 1KB/load
}

// Exact pow2 renorm at EVERY level (R1 lesson: skip-norm is unsafe).
__device__ __forceinline__ void prod_norm(const float av[16], const float bv[16],
                                          float MA, float MB,
                                          float p[16], float& Mrow) {
    float pv[16];
    #pragma unroll
    for (int i = 0; i < 16; ++i) pv[i] = av[i] * bv[i];
    const float rm = rmax16(pv);
    const int e = (int)((__float_as_uint(rm) >> 23) & 0xFF) - 127;
    #pragma unroll
    for (int i = 0; i < 16; ++i) p[i] = ldexpf(pv[i], -e);   // exact scaling
    Mrow = MA + MB + (float)e;
}

// rowStart = absolute batch row of this lane-group's m=0
__device__ __forceinline__ void gauss_p(const Op& op,
    const float* __restrict__ xT, const float* __restrict__ Ag,
    const float* __restrict__ Bg, const float* __restrict__ Cg,
    int rowStart, int m, int q, float p[16], float& Mrow)
{
    const int d0 = op.c0, d1 = op.c1;
    const float xv0 = xT[d0 * 2048 + rowStart + m];
    const float xv1 = xT[d1 * 2048 + rowStart + m];
    const float x0s = xv0 * xv0, x1s = xv1 * xv1;
    float hv[16];
    #pragma unroll
    for (int kh = 0; kh < 2; ++kh) {
        const int kb = kh * 32 + q * 8;
        F8v A0 = ld8(Ag + d0*64 + kb), B0 = ld8(Bg + d0*64 + kb);
        F8v C0 = ld8(Cg + d0*64 + kb);
        F8v A1 = ld8(Ag + d1*64 + kb), B1 = ld8(Bg + d1*64 + kb);
        F8v C1 = ld8(Cg + d1*64 + kb);
        #pragma unroll
        for (int i = 0; i < 8; ++i) {
            float t0 = fmaf(A0.v[i], x0s, C0.v[i]);
            t0 = fmaf(B0.v[i], xv0, t0);
            float t1 = fmaf(A1.v[i], x1s, C1.v[i]);
            t1 = fmaf(B1.v[i], xv1, t1);
            hv[kh*8+i] = t0 + t1;
        }
    }
    const float hm = rmax16(hv);
    #pragma unroll
    for (int i = 0; i < 16; ++i) p[i] = __builtin_amdgcn_exp2f(hv[i] - hm);
    Mrow = hm;
}

__device__ __forceinline__ void gprod_p(const Op& op,
    const unsigned short* __restrict__ inAcc, const float* __restrict__ inM,
    int rowStart, int m, int q, float p[16], float& Mrow)
{
    const int4* A4 = (const int4*)(inAcc + (size_t)(op.c0 * 2048 + rowStart + m) * 64);
    const int4* B4 = (const int4*)(inAcc + (size_t)(op.c1 * 2048 + rowStart + m) * 64);
    float av[16], bv[16];
    up8(A4[q], av); up8(A4[4+q], av + 8);
    up8(B4[q], bv); up8(B4[4+q], bv + 8);
    prod_norm(av, bv, inM[op.c0 * 2048 + rowStart + m],
              inM[op.c1 * 2048 + rowStart + m], p, Mrow);
}

// rowBase = 0 or 16 within the 32-row tile
__device__ __forceinline__ void slot_prod(const unsigned short* slotS, const float* Mslot,
                                          int sA, int sB, int rowBase, int m, int q,
                                          float p[16], float& Mrow)
{
    const int4* A4 = (const int4*)(slotS + sA * 32 * SROW + (rowBase + m) * SROW);
    const int4* B4 = (const int4*)(slotS + sB * 32 * SROW + (rowBase + m) * SROW);
    float av[16], bv[16];
    up8(A4[q], av); up8(A4[4+q], av + 8);
    up8(B4[q], bv); up8(B4[4+q], bv + 8);
    prod_norm(av, bv, Mslot[sA * 32 + rowBase + m],
              Mslot[sB * 32 + rowBase + m], p, Mrow);
}

__device__ __forceinline__ void mfma8(const float p[16], const int4 bf[8], f32x4 acc[4]) {
    bf16x8 a0, a1;
    pack_p(p, a0, a1);
    #pragma unroll
    for (int jt = 0; jt < 4; ++jt) {
        f32x4 z = {0.f, 0.f, 0.f, 0.f};
        z = __builtin_amdgcn_mfma_f32_16x16x32_bf16(a0, *(bf16x8*)&bf[jt*2+0], z, 0, 0, 0);
        z = __builtin_amdgcn_mfma_f32_16x16x32_bf16(a1, *(bf16x8*)&bf[jt*2+1], z, 0, 0, 0);
        acc[jt] = z;
    }
}

__device__ __forceinline__ void store_slot(unsigned short* slotS, float* Mslot,
                                           int sl, int rowBase, const f32x4 acc[4],
                                           float Mrow, int m, int q)
{
    unsigned short* S = slotS + sl * 32 * SROW;
    #pragma unroll
    for (int jt = 0; jt < 4; ++jt)
        #pragma unroll
        for (int r = 0; r < 4; ++r)
            S[(rowBase + q*4 + r) * SROW + jt*16 + m] = (unsigned short)bfr(acc[jt][r]);
    if (q == 0) Mslot[sl * 32 + rowBase + m] = Mrow;
}

__device__ __forceinline__ void wave_fence() {
    __builtin_amdgcn_wave_barrier();
    __builtin_amdgcn_s_waitcnt(0xC07F);   // lgkmcnt(0)
    __builtin_amdgcn_wave_barrier();
}

// Mix compute using PRE-LOADED weight fragments (R8-proven prefetch).
// NH=2: both 16-row halves ILP-paired (R3-proven). NH=1: single half.
template<int NH>
__device__ __forceinline__ void mix_core(const int4 bf[8],
    unsigned short* slotS, float* Mslot,
    int sA, int sB, int sD, int m, int q)
{
    if constexpr (NH == 2) {
        float p0[16], p1[16], M0, M1;
        slot_prod(slotS, Mslot, sA, sB, 0,  m, q, p0, M0);
        slot_prod(slotS, Mslot, sA, sB, 16, m, q, p1, M1);
        f32x4 acc0[4], acc1[4];
        mfma8(p0, bf, acc0);
        mfma8(p1, bf, acc1);
        store_slot(slotS, Mslot, sD, 0,  acc0, M0, m, q);
        store_slot(slotS, Mslot, sD, 16, acc1, M1, m, q);
    } else {
        float p[16], M;
        slot_prod(slotS, Mslot, sA, sB, 0, m, q, p, M);
        f32x4 acc[4];
        mfma8(p, bf, acc);
        store_slot(slotS, Mslot, sD, 0, acc, M, m, q);
    }
}

// ---------------------------------------------------------------------------
// 4-wave cooperative tree kernel — CONVERGED best (R10, 128.3us): dual-half
// ILP per op, cross-phase weight prefetch (R8), unclamped bounds (R7),
// 1D XCD swizzle (R10). Session ledger: prep rewrite -6.5us, prefetch -2.5,
// XCD swizzle -1.3, tail split -0.9. Explored and rejected: 8-wave blocks
// (-6), 16-row TLP split (~2x), last-arriver fusion (-34), occupancy clamps
// (spill), 2D tree-x-tile swizzle (null), direct-x leaves (null). Remaining
// time is latency/fixed-cost floor: 3 dependent dispatches + serial
// 4-op+renorm chain/block at ~2% MFMA / ~9% HBM (nothing saturated).
//   wave w: leaves 2w,2w+1 -> slots 2w,2w+1 ; L2 mix w: 2w,2w+1 -> 2w
//   L3 u (waves 0,2): 4u,4u+2 -> 4u ; root (wave 0): 0,4
// MODE 0 (K14, levels 1-4): 32-row tiles dual-half -> L4 acc+M.
// MODE 1 (tail, levels 5-8): 16-row tiles single-half -> d_out.
// ---------------------------------------------------------------------------
template<int MODE>
__global__ __launch_bounds__(256) void circuit_coop(
    const unsigned short* __restrict__ wbJ,
    const Op* __restrict__ schedG, int ntile,
    const float* __restrict__ xT, const float* __restrict__ Ag,
    const float* __restrict__ Bg, const float* __restrict__ Cg,
    const unsigned short* __restrict__ inAcc, const float* __restrict__ inM,
    unsigned short* __restrict__ outAcc, float* __restrict__ outM,
    float* __restrict__ outLog)
{
    constexpr int NH = (MODE == 0) ? 2 : 1;
    __shared__ __align__(16) unsigned short slotS[8 * 32 * SROW];  // 36.9 KB
    __shared__ float Mslot[8 * 32];
    __shared__ Op ops[16];

    const int t    = threadIdx.x;
    const int wv   = t >> 6;
    const int lane = t & 63;
    const int m    = lane & 15;
    const int q    = lane >> 4;
    int s, b0;
    if constexpr (MODE == 0) {
        // XCD swizzle (R10-proven): XCD k (= blockIdx&7) owns trees 2k,2k+1.
        const int xcd = blockIdx.x & 7;
        const int idx = blockIdx.x >> 3;          // 0..127
        s  = (xcd << 1) | (idx >> 6);             // tree 0..15
        b0 = (idx & 63) * 32;                     // tile row base
    } else {
        s  = blockIdx.x / ntile;
        b0 = (blockIdx.x % ntile) * 16;
    }

    if (t < 15) *(int4*)&ops[t] = ((const int4*)(schedG + s * 15))[t];
    __syncthreads();

    // ---- prefetch: phase-2 weights issued NOW, drain under phase 1
    int4 bf2[8];
    load_bfrag(wbJ, ops[8 + wv].w, lane, bf2);

    // ---- phase 1: 2 leaves per wave
    #pragma unroll
    for (int i = 0; i < 2; ++i) {
        const int sl = 2 * wv + i;
        const Op op = ops[sl];
        int4 bf[8];
        load_bfrag(wbJ, op.w, lane, bf);
        if constexpr (NH == 2) {
            float p0[16], p1[16], M0, M1;
            if (MODE == 0) {
                gauss_p(op, xT, Ag, Bg, Cg, b0,      m, q, p0, M0);
                gauss_p(op, xT, Ag, Bg, Cg, b0 + 16, m, q, p1, M1);
            } else {
                gprod_p(op, inAcc, inM, b0,      m, q, p0, M0);
                gprod_p(op, inAcc, inM, b0 + 16, m, q, p1, M1);
            }
            f32x4 acc0[4], acc1[4];
            mfma8(p0, bf, acc0);
            mfma8(p1, bf, acc1);
            store_slot(slotS, Mslot, sl, 0,  acc0, M0, m, q);
            store_slot(slotS, Mslot, sl, 16, acc1, M1, m, q);
        } else {
            float p[16], M;
            if (MODE == 0) gauss_p(op, xT, Ag, Bg, Cg, b0, m, q, p, M);
            else           gprod_p(op, inAcc, inM, b0, m, q, p, M);
            f32x4 acc[4];
            mfma8(p, bf, acc);
            store_slot(slotS, Mslot, sl, 0, acc, M, m, q);
        }
    }
    wave_fence();

    // ---- prefetch: phase-3 weights (waves 0,2) before phase-2 compute
    const int u = wv >> 1;
    int4 bf3[8];
    if ((wv & 1) == 0) load_bfrag(wbJ, ops[12 + u].w, lane, bf3);

    // ---- phase 2: L2 mix j = wv, reads own slots 2j,2j+1 -> 2j
    mix_core<NH>(bf2, slotS, Mslot, 2*wv, 2*wv + 1, 2*wv, m, q);
    __syncthreads();

    // ---- phase 3: L3 mix u on waves 0,2 (wave 0 prefetches root weights)
    int4 bf4[8];
    if ((wv & 1) == 0) {
        if (wv == 0) load_bfrag(wbJ, ops[14].w, lane, bf4);
        mix_core<NH>(bf3, slotS, Mslot, 4*u, 4*u + 2, 4*u, m, q);
    }
    __syncthreads();

    // ---- phase 4: root (wave 0): reads slots 0,4 with preloaded bf4
    if (wv == 0) {
        if constexpr (NH == 2) {   // MODE 0 epilogue: L4 acc+M
            float p0[16], p1[16], M0, M1;
            slot_prod(slotS, Mslot, 0, 4, 0,  m, q, p0, M0);
            slot_prod(slotS, Mslot, 0, 4, 16, m, q, p1, M1);
            f32x4 acc0[4], acc1[4];
            mfma8(p0, bf4, acc0);
            mfma8(p1, bf4, acc1);
            const int rowOff = s * 2048 + b0;
            #pragma unroll
            for (int jt = 0; jt < 4; ++jt)
                #pragma unroll
                for (int r = 0; r < 4; ++r) {
                    outAcc[(size_t)(rowOff +      q*4 + r) * 64 + jt*16 + m] =
                        (unsigned short)bfr(acc0[jt][r]);
                    outAcc[(size_t)(rowOff + 16 + q*4 + r) * 64 + jt*16 + m] =
                        (unsigned short)bfr(acc1[jt][r]);
                }
            if (q == 0) {
                outM[rowOff + m]      = M0;
                outM[rowOff + 16 + m] = M1;
            }
        } else {                    // MODE 1 epilogue: final natural-log output
            float p0[16], M0;
            slot_prod(slotS, Mslot, 0, 4, 0, m, q, p0, M0);
            f32x4 acc0[4];
            mfma8(p0, bf4, acc0);
            float mr0[4];
            #pragma unroll
            for (int r = 0; r < 4; ++r) mr0[r] = __shfl(M0, q * 4 + r, 64);
            #pragma unroll
            for (int jt = 0; jt < 4; ++jt)
                #pragma unroll
                for (int r = 0; r < 4; ++r)
                    outLog[(b0 + q*4 + r) * 64 + jt*16 + m] =
                        (__builtin_amdgcn_logf(acc0[jt][r]) + mr0[r]) * LN2_F;
        }
    }
}

// ---------------------------------------------------------------------------
// d_in order: 0:x 1:mu 2:log_sigma 3:in_scope_idx, then fold_idx{l}, w{l}
// ---------------------------------------------------------------------------
extern "C" void kernel_launch(void* const* d_in, const int* in_sizes, int n_in,
                              void* d_out, int out_size, void* d_ws, size_t ws_size,
                              hipStream_t stream) {
    const float* x     = (const float*)d_in[0];
    const float* mu    = (const float*)d_in[1];
    const float* lsg   = (const float*)d_in[2];
    const int*   scope = (const int*)d_in[3];
    const int*   f1 = (const int*)d_in[4];   const float* w1 = (const float*)d_in[5];
    const int*   f2 = (const int*)d_in[6];   const float* w2 = (const float*)d_in[7];
    const int*   f3 = (const int*)d_in[8];   const float* w3 = (const float*)d_in[9];
    const int*   f4 = (const int*)d_in[10];  const float* w4 = (const float*)d_in[11];
    const int*   f5 = (const int*)d_in[12];  const float* w5 = (const float*)d_in[13];
    const int*   f6 = (const int*)d_in[14];  const float* w6 = (const float*)d_in[15];
    const int*   f7 = (const int*)d_in[16];  const float* w7 = (const float*)d_in[17];
    const int*   f8 = (const int*)d_in[18];  const float* w8 = (const float*)d_in[19];

    char* ws = (char*)d_ws;
    const unsigned short* wbJ = (const unsigned short*)(ws + WS_WBJ);
    const float* Ag  = (const float*)(ws + WS_A);
    const float* Bg  = (const float*)(ws + WS_B);
    const float* Cg  = (const float*)(ws + WS_C);
    const float* xT  = (const float*)(ws + WS_XT);
    const Op*    sch = (const Op*)(ws + WS_SCHED);
    unsigned short* L4A = (unsigned short*)(ws + WS_L4A);
    float*          L4M = (float*)(ws + WS_L4M);

    prep_kernel<<<576, 256, 0, stream>>>(w1, w2, w3, w4, w5, w6, w7, w8,
                                         mu, lsg, x, scope,
                                         f1, f2, f3, f4, f5, f6, f7, f8, ws);

    // levels 1..4: 16 trees x 64 tiles of 32 rows, 4-wave cooperative trees
    circuit_coop<0><<<1024, 256, 0, stream>>>(
        wbJ, sch, 64,
        xT, Ag, Bg, Cg,
        nullptr, nullptr,
        L4A, L4M, nullptr);

    // levels 5..8: 128 tiles of 16 rows
    circuit_coop<1><<<128, 256, 0, stream>>>(
        wbJ, sch + 240, 128,
        nullptr, nullptr, nullptr, nullptr,
        L4A, L4M,
        nullptr, nullptr, (float*)d_out);
}